// Round 4
// baseline (281.972 us; speedup 1.0000x reference)
//
#include <hip/hip_runtime.h>

// BERT-CRF fused. Shapes: B=64, S=512, E=1024, T=9.
// d_out: [0]=llh, [1 .. 1+B*S*T)=emission (B,S,T) fp32.
//
// emis_kernel: lane = 16*r + m; each 16-lane quadrant owns one row (4 rows
//   per wave), covering K=1024 in 16 float4 iters. Reduction = 4 butterfly
//   levels within the quadrant (36 DS ops/wave vs 216 for 64-wide x 9 tags).
//   W reads identical across quadrants (L1 broadcast); x reads coalesced
//   (4 x 256B segments/instr). HBM floor ~24 us (134 MB read + 18 MB write).
//
// CRF scan in LINEAR space: em is log_softmax so exp(em) rows sum to 1;
// transfer matrices M_s = exp(trans) o diag(exp(em_s)) have row sums
// ~e^{+-0.1}; 511-step products stay fp32-safe, no rescaling, no LSE chain.
//   crf_chunk: 4096 waves (64 b x 64 chunks of 8 steps), 9x9 product in regs,
//     masked steps = identity. Writes matrices to d_ws (4096*81*4 = 1.33 MB).
//   crf_final: 64 blocks x 256: numerator + LDS tree reduction (depth 6,
//     append-buffer), den = log(v0^T Mtot e^end), atomicAdd into out[0]
//     (zeroed by emis block 0 each call).

#define BB 64
#define SS 512
#define EE 1024
#define TT 9

__global__ __launch_bounds__(256) void emis_kernel(
    const float* __restrict__ embed,   // (B*S, E)
    const float* __restrict__ W,       // (T, E)
    const float* __restrict__ bias,    // (T)
    float* __restrict__ out)           // [0]=llh, [1..]=emission
{
    if (blockIdx.x == 0 && threadIdx.x == 0) out[0] = 0.0f;  // llh accumulator

    const int wid  = threadIdx.x >> 6;
    const int lane = threadIdx.x & 63;
    const int r    = lane >> 4;        // quadrant = row within wave
    const int m    = lane & 15;        // K-split index within quadrant
    const int row  = blockIdx.x * 16 + wid * 4 + r;

    float acc[TT];
#pragma unroll
    for (int t = 0; t < TT; ++t) acc[t] = 0.0f;

    const float* xrow = embed + (size_t)row * EE;

    // K=1024 = 16 iters x (16 lanes x 4 floats)
#pragma unroll 4
    for (int i = 0; i < 16; ++i) {
        const int off = i * 64 + 4 * m;
        const float4 x = *(const float4*)(xrow + off);
#pragma unroll
        for (int t = 0; t < TT; ++t) {
            const float4 w = *(const float4*)(W + t * EE + off);
            acc[t] += x.x * w.x + x.y * w.y + x.z * w.z + x.w * w.w;
        }
    }

    // Reduce within the 16-lane quadrant: 4 levels x 9 tags = 36 DS ops.
#pragma unroll
    for (int t = 0; t < TT; ++t) {
#pragma unroll
        for (int o = 8; o > 0; o >>= 1)
            acc[t] += __shfl_xor(acc[t], o, 64);
        acc[t] += bias[t];  // uniform scalar load
    }

    // log_softmax over T=9 (replicated within quadrant; registers only)
    float mx = acc[0];
#pragma unroll
    for (int t = 1; t < TT; ++t) mx = fmaxf(mx, acc[t]);
    float ssum = 0.0f;
#pragma unroll
    for (int t = 0; t < TT; ++t) ssum += __expf(acc[t] - mx);
    const float lse = mx + __logf(ssum);

    // Lane m (<9) of each quadrant stores element m of its row: one store
    // instr covers 4 rows = 144 contiguous bytes.
    float val = acc[0];
#pragma unroll
    for (int t = 1; t < TT; ++t) val = (m == t) ? acc[t] : val;
    if (m < TT)
        out[1 + (size_t)row * TT + m] = val - lse;
}

// ---- CRF stage 1: per-chunk linear-space matrix products ----
__global__ __launch_bounds__(256) void crf_chunk(
    const float* __restrict__ outbase,  // d_out ([0]=llh, em at +1)
    const int* __restrict__ mask,       // (B,S)
    const float* __restrict__ trans,    // (T,T)
    float* __restrict__ ws)             // (B*64) matrices of 81 floats
{
    const int gw   = (blockIdx.x * 256 + threadIdx.x) >> 6;  // 0..4095
    const int lane = threadIdx.x & 63;
    const int b = gw >> 6;        // batch
    const int c = gw & 63;        // chunk
    const int i = (lane < TT) ? lane : 0;  // row of chunk product

    const float* em = outbase + 1 + (size_t)b * SS * TT;

    // E = exp(trans): lane-uniform, 81 VGPRs
    float E[TT * TT];
#pragma unroll
    for (int e = 0; e < TT * TT; ++e) E[e] = __expf(trans[e]);

    // first step of this chunk: s0 = 8c+1
    const int s0 = 8 * c + 1;
    float R[TT];
    {
        float p[TT];
#pragma unroll
        for (int j = 0; j < TT; ++j) p[j] = __expf(em[s0 * TT + j]);
        const int mk = mask[b * SS + s0];
#pragma unroll
        for (int k = 0; k < TT; ++k)
            R[k] = mk ? (E[i * TT + k] * p[k]) : ((k == i) ? 1.0f : 0.0f);
    }
#pragma unroll
    for (int d = 1; d < 8; ++d) {
        const int s = s0 + d;
        const bool valid = (s < SS);          // chunk 63 has only 7 steps
        const int sc = valid ? s : (SS - 1);
        float p[TT];
#pragma unroll
        for (int j = 0; j < TT; ++j) p[j] = __expf(em[sc * TT + j]);
        const int mk = valid ? mask[b * SS + sc] : 0;  // invalid/masked -> identity

        float nR[TT];
#pragma unroll
        for (int j = 0; j < TT; ++j) {
            float a = 0.0f;
#pragma unroll
            for (int k = 0; k < TT; ++k) a += R[k] * E[k * TT + j];
            nR[j] = a * p[j];
        }
#pragma unroll
        for (int j = 0; j < TT; ++j) R[j] = mk ? nR[j] : R[j];
    }
    if (lane < TT) {
#pragma unroll
        for (int j = 0; j < TT; ++j)
            ws[(size_t)gw * 81 + i * TT + j] = R[j];
    }
}

// ---- CRF stage 2: per-batch tree reduction + numerator + llh ----
__global__ __launch_bounds__(256) void crf_final(
    const float* __restrict__ outbase,
    const int* __restrict__ tags,
    const int* __restrict__ mask,
    const float* __restrict__ start_t,
    const float* __restrict__ end_t,
    const float* __restrict__ trans,
    const float* __restrict__ ws,
    float* __restrict__ out)
{
    __shared__ float mats[127 * 81];   // 64 in + 32+16+8+4+2+1 level outputs
    __shared__ float red[4];
    __shared__ float redm[4];

    const int b = blockIdx.x;
    const int tid = threadIdx.x;
    const int lane = tid & 63, wid = tid >> 6;
    const float* em = outbase + 1 + (size_t)b * SS * TT;

    for (int idx = tid; idx < 64 * 81; idx += 256)
        mats[idx] = ws[(size_t)b * 64 * 81 + idx];

    // ---- numerator: threads cover s = tid, tid+256 ----
    float num = 0.0f;
    int msum = 0;
    for (int s = tid; s < SS; s += 256) {
        const int mk = mask[b * SS + s];
        msum += mk;
        const int tg = tags[b * SS + s];
        if (s == 0) {
            num += start_t[tg] + em[tg];
        } else {
            const int tp = tags[b * SS + s - 1];
            num += (float)mk * (trans[tp * TT + tg] + em[s * TT + tg]);
        }
    }
#pragma unroll
    for (int o = 32; o > 0; o >>= 1) {
        num += __shfl_xor(num, o, 64);
        msum += __shfl_xor(msum, o, 64);
    }
    if (lane == 0) { red[wid] = num; redm[wid] = (float)msum; }
    __syncthreads();

    // ---- tree reduction: levels n = 32,16,8,4,2,1, append-buffer ----
    int inOff = 0, outOff = 64;
    for (int n = 32; n >= 1; n >>= 1) {
        for (int c = wid; c < n; c += 4) {
            const float* A  = mats + (inOff + 2 * c) * 81;
            const float* Bm = mats + (inOff + 2 * c + 1) * 81;
            float* C = mats + (outOff + c) * 81;
            int e = lane;                       // entries 0..63
            int ii = e / 9, jj = e - ii * 9;
            float a = 0.0f;
#pragma unroll
            for (int k = 0; k < TT; ++k) a += A[ii * 9 + k] * Bm[k * 9 + jj];
            C[e] = a;
            if (lane < 17) {                    // entries 64..80
                e = 64 + lane; ii = e / 9; jj = e - ii * 9;
                float a2 = 0.0f;
#pragma unroll
                for (int k = 0; k < TT; ++k) a2 += A[ii * 9 + k] * Bm[k * 9 + jj];
                C[e] = a2;
            }
        }
        __syncthreads();
        inOff = outOff; outOff += n;
    }
    // Mtot at mats + 126*81

    if (wid == 0) {
        const float* Mt = mats + 126 * 81;
        float v0[TT];
#pragma unroll
        for (int i2 = 0; i2 < TT; ++i2) v0[i2] = __expf(start_t[i2] + em[i2]);
        const int j = (lane < TT) ? lane : 0;
        float cs = 0.0f;
#pragma unroll
        for (int i2 = 0; i2 < TT; ++i2) cs += v0[i2] * Mt[i2 * 9 + j];
        float val = cs * __expf(end_t[j]);
        if (lane >= TT) val = 0.0f;
        // sum lanes 0..8 (lanes 9..15 are zero) via width-16 butterfly
#pragma unroll
        for (int o = 8; o > 0; o >>= 1) val += __shfl_xor(val, o, 64);
        if (lane == 0) {
            const float den = __logf(val);
            float numT = red[0] + red[1] + red[2] + red[3];
            const int ms = (int)(redm[0] + redm[1] + redm[2] + redm[3]);
            numT += end_t[tags[b * SS + (ms - 1)]];
            atomicAdd(out, numT - den);
        }
    }
}

extern "C" void kernel_launch(void* const* d_in, const int* in_sizes, int n_in,
                              void* d_out, int out_size, void* d_ws, size_t ws_size,
                              hipStream_t stream) {
    const float* embed   = (const float*)d_in[0];
    const int*   tags    = (const int*)d_in[1];
    const int*   mask    = (const int*)d_in[2];
    const float* W       = (const float*)d_in[3];
    const float* bias    = (const float*)d_in[4];
    const float* start_t = (const float*)d_in[5];
    const float* end_t   = (const float*)d_in[6];
    const float* trans   = (const float*)d_in[7];
    float* out = (float*)d_out;
    float* ws  = (float*)d_ws;   // needs 4096*81*4 = 1.33 MB

    // 32768 rows / 16 rows per block
    emis_kernel<<<2048, 256, 0, stream>>>(embed, W, bias, out);
    // 4096 chunk-waves / 4 waves per block
    crf_chunk<<<1024, 256, 0, stream>>>(out, mask, trans, ws);
    // one block per batch
    crf_final<<<BB, 256, 0, stream>>>(out, tags, mask, start_t, end_t, trans, ws, out);
}

// Round 5
// 257.056 us; speedup vs baseline: 1.0969x; 1.0969x over previous
//
#include <hip/hip_runtime.h>

// BERT-CRF fused. Shapes: B=64, S=512, E=1024, T=9.
// d_out: [0]=llh, [1 .. 1+B*S*T)=emission (B,S,T) fp32.
//
// emis_kernel: block=512 (8 waves), 2 rows/wave, 16 rows/block.
//   W (36 KB) staged to LDS ONCE per block -> kills the redundant W traffic
//   through the vector-memory path that limited R2-R4 (1.2 GB of L1 reads).
//   Each wave prefetches its 2 rows of x (8 independent float4 loads) before
//   the staging barrier; compute = 4 chunks x 9 conflict-free ds_read_b128 +
//   72 FMA; 6-level butterfly reduce (108 DS ops/wave), in-register
//   log_softmax, lanes 0..8 store.
//
// CRF scan in LINEAR space: em is log_softmax so exp(em) rows sum to 1;
// transfer matrices M_s = exp(trans) o diag(exp(em_s)) have row sums
// ~e^{+-0.1}; 511-step products stay fp32-safe, no rescaling, no LSE chain.
//   crf_chunk: 4096 waves (64 b x 64 chunks of 8 steps), 9x9 product in regs,
//     masked steps = identity. Writes matrices to d_ws (4096*81*4 = 1.33 MB).
//   crf_final: 64 blocks x 256: numerator + LDS tree reduction (depth 6,
//     append-buffer), den = log(v0^T Mtot e^end), atomicAdd into out[0]
//     (zeroed by emis block 0 each call).

#define BB 64
#define SS 512
#define EE 1024
#define TT 9

__global__ __launch_bounds__(512) void emis_kernel(
    const float* __restrict__ embed,   // (B*S, E)
    const float* __restrict__ W,       // (T, E)
    const float* __restrict__ bias,    // (T)
    float* __restrict__ out)           // [0]=llh, [1..]=emission
{
    __shared__ float Wlds[TT * EE];    // 36 KB

    if (blockIdx.x == 0 && threadIdx.x == 0) out[0] = 0.0f;  // llh accumulator

    const int tid  = threadIdx.x;
    const int wid  = tid >> 6;
    const int lane = tid & 63;
    const int row0 = blockIdx.x * 16 + wid * 2;   // 2 rows per wave

    // Prefetch x for both rows (8 independent float4 loads, max MLP),
    // issued before the staging barrier.
    float4 x0[4], x1[4];
#pragma unroll
    for (int c = 0; c < 4; ++c) {
        const int off = c * 256 + 4 * lane;
        x0[c] = *(const float4*)(embed + (size_t)row0 * EE + off);
        x1[c] = *(const float4*)(embed + (size_t)(row0 + 1) * EE + off);
    }

    // Stage all of W into LDS (2304 float4s, 512 threads -> 4.5 iters).
    const float4* W4 = (const float4*)W;
    float4* Wl4 = (float4*)Wlds;
    for (int idx = tid; idx < (TT * EE) / 4; idx += 512)
        Wl4[idx] = W4[idx];
    __syncthreads();

    float acc0[TT], acc1[TT];
#pragma unroll
    for (int t = 0; t < TT; ++t) { acc0[t] = 0.0f; acc1[t] = 0.0f; }

#pragma unroll
    for (int c = 0; c < 4; ++c) {
        const int off = c * 256 + 4 * lane;
#pragma unroll
        for (int t = 0; t < TT; ++t) {
            const float4 w = *(const float4*)(Wlds + t * EE + off);  // ds_read_b128
            acc0[t] += x0[c].x * w.x + x0[c].y * w.y + x0[c].z * w.z + x0[c].w * w.w;
            acc1[t] += x1[c].x * w.x + x1[c].y * w.y + x1[c].z * w.z + x1[c].w * w.w;
        }
    }

    // 6-level butterfly over 64 lanes, 9 tags x 2 rows.
#pragma unroll
    for (int t = 0; t < TT; ++t) {
#pragma unroll
        for (int o = 32; o > 0; o >>= 1) {
            acc0[t] += __shfl_xor(acc0[t], o, 64);
            acc1[t] += __shfl_xor(acc1[t], o, 64);
        }
        const float bt = bias[t];
        acc0[t] += bt; acc1[t] += bt;
    }

    // log_softmax over T=9 (registers only), then lanes 0..8 store.
#pragma unroll
    for (int r = 0; r < 2; ++r) {
        float* acc = r ? acc1 : acc0;
        float mx = acc[0];
#pragma unroll
        for (int t = 1; t < TT; ++t) mx = fmaxf(mx, acc[t]);
        float ssum = 0.0f;
#pragma unroll
        for (int t = 0; t < TT; ++t) ssum += __expf(acc[t] - mx);
        const float lse = mx + __logf(ssum);

        float val = acc[0];
#pragma unroll
        for (int t = 1; t < TT; ++t) val = (lane == t) ? acc[t] : val;
        if (lane < TT)
            out[1 + (size_t)(row0 + r) * TT + lane] = val - lse;
    }
}

// ---- CRF stage 1: per-chunk linear-space matrix products ----
__global__ __launch_bounds__(256) void crf_chunk(
    const float* __restrict__ outbase,  // d_out ([0]=llh, em at +1)
    const int* __restrict__ mask,       // (B,S)
    const float* __restrict__ trans,    // (T,T)
    float* __restrict__ ws)             // (B*64) matrices of 81 floats
{
    const int gw   = (blockIdx.x * 256 + threadIdx.x) >> 6;  // 0..4095
    const int lane = threadIdx.x & 63;
    const int b = gw >> 6;        // batch
    const int c = gw & 63;        // chunk
    const int i = (lane < TT) ? lane : 0;  // row of chunk product

    const float* em = outbase + 1 + (size_t)b * SS * TT;

    // E = exp(trans): lane-uniform, 81 VGPRs
    float E[TT * TT];
#pragma unroll
    for (int e = 0; e < TT * TT; ++e) E[e] = __expf(trans[e]);

    // first step of this chunk: s0 = 8c+1
    const int s0 = 8 * c + 1;
    float R[TT];
    {
        float p[TT];
#pragma unroll
        for (int j = 0; j < TT; ++j) p[j] = __expf(em[s0 * TT + j]);
        const int mk = mask[b * SS + s0];
#pragma unroll
        for (int k = 0; k < TT; ++k)
            R[k] = mk ? (E[i * TT + k] * p[k]) : ((k == i) ? 1.0f : 0.0f);
    }
#pragma unroll
    for (int d = 1; d < 8; ++d) {
        const int s = s0 + d;
        const bool valid = (s < SS);          // chunk 63 has only 7 steps
        const int sc = valid ? s : (SS - 1);
        float p[TT];
#pragma unroll
        for (int j = 0; j < TT; ++j) p[j] = __expf(em[sc * TT + j]);
        const int mk = valid ? mask[b * SS + sc] : 0;  // invalid/masked -> identity

        float nR[TT];
#pragma unroll
        for (int j = 0; j < TT; ++j) {
            float a = 0.0f;
#pragma unroll
            for (int k = 0; k < TT; ++k) a += R[k] * E[k * TT + j];
            nR[j] = a * p[j];
        }
#pragma unroll
        for (int j = 0; j < TT; ++j) R[j] = mk ? nR[j] : R[j];
    }
    if (lane < TT) {
#pragma unroll
        for (int j = 0; j < TT; ++j)
            ws[(size_t)gw * 81 + i * TT + j] = R[j];
    }
}

// ---- CRF stage 2: per-batch tree reduction + numerator + llh ----
__global__ __launch_bounds__(256) void crf_final(
    const float* __restrict__ outbase,
    const int* __restrict__ tags,
    const int* __restrict__ mask,
    const float* __restrict__ start_t,
    const float* __restrict__ end_t,
    const float* __restrict__ trans,
    const float* __restrict__ ws,
    float* __restrict__ out)
{
    __shared__ float mats[127 * 81];   // 64 in + 32+16+8+4+2+1 level outputs
    __shared__ float red[4];
    __shared__ float redm[4];

    const int b = blockIdx.x;
    const int tid = threadIdx.x;
    const int lane = tid & 63, wid = tid >> 6;
    const float* em = outbase + 1 + (size_t)b * SS * TT;

    for (int idx = tid; idx < 64 * 81; idx += 256)
        mats[idx] = ws[(size_t)b * 64 * 81 + idx];

    // ---- numerator: threads cover s = tid, tid+256 ----
    float num = 0.0f;
    int msum = 0;
    for (int s = tid; s < SS; s += 256) {
        const int mk = mask[b * SS + s];
        msum += mk;
        const int tg = tags[b * SS + s];
        if (s == 0) {
            num += start_t[tg] + em[tg];
        } else {
            const int tp = tags[b * SS + s - 1];
            num += (float)mk * (trans[tp * TT + tg] + em[s * TT + tg]);
        }
    }
#pragma unroll
    for (int o = 32; o > 0; o >>= 1) {
        num += __shfl_xor(num, o, 64);
        msum += __shfl_xor(msum, o, 64);
    }
    if (lane == 0) { red[wid] = num; redm[wid] = (float)msum; }
    __syncthreads();

    // ---- tree reduction: levels n = 32,16,8,4,2,1, append-buffer ----
    int inOff = 0, outOff = 64;
    for (int n = 32; n >= 1; n >>= 1) {
        for (int c = wid; c < n; c += 4) {
            const float* A  = mats + (inOff + 2 * c) * 81;
            const float* Bm = mats + (inOff + 2 * c + 1) * 81;
            float* C = mats + (outOff + c) * 81;
            int e = lane;                       // entries 0..63
            int ii = e / 9, jj = e - ii * 9;
            float a = 0.0f;
#pragma unroll
            for (int k = 0; k < TT; ++k) a += A[ii * 9 + k] * Bm[k * 9 + jj];
            C[e] = a;
            if (lane < 17) {                    // entries 64..80
                e = 64 + lane; ii = e / 9; jj = e - ii * 9;
                float a2 = 0.0f;
#pragma unroll
                for (int k = 0; k < TT; ++k) a2 += A[ii * 9 + k] * Bm[k * 9 + jj];
                C[e] = a2;
            }
        }
        __syncthreads();
        inOff = outOff; outOff += n;
    }
    // Mtot at mats + 126*81

    if (wid == 0) {
        const float* Mt = mats + 126 * 81;
        float v0[TT];
#pragma unroll
        for (int i2 = 0; i2 < TT; ++i2) v0[i2] = __expf(start_t[i2] + em[i2]);
        const int j = (lane < TT) ? lane : 0;
        float cs = 0.0f;
#pragma unroll
        for (int i2 = 0; i2 < TT; ++i2) cs += v0[i2] * Mt[i2 * 9 + j];
        float val = cs * __expf(end_t[j]);
        if (lane >= TT) val = 0.0f;
        // sum lanes 0..8 (lanes 9..15 are zero) via width-16 butterfly
#pragma unroll
        for (int o = 8; o > 0; o >>= 1) val += __shfl_xor(val, o, 64);
        if (lane == 0) {
            const float den = __logf(val);
            float numT = red[0] + red[1] + red[2] + red[3];
            const int ms = (int)(redm[0] + redm[1] + redm[2] + redm[3]);
            numT += end_t[tags[b * SS + (ms - 1)]];
            atomicAdd(out, numT - den);
        }
    }
}

extern "C" void kernel_launch(void* const* d_in, const int* in_sizes, int n_in,
                              void* d_out, int out_size, void* d_ws, size_t ws_size,
                              hipStream_t stream) {
    const float* embed   = (const float*)d_in[0];
    const int*   tags    = (const int*)d_in[1];
    const int*   mask    = (const int*)d_in[2];
    const float* W       = (const float*)d_in[3];
    const float* bias    = (const float*)d_in[4];
    const float* start_t = (const float*)d_in[5];
    const float* end_t   = (const float*)d_in[6];
    const float* trans   = (const float*)d_in[7];
    float* out = (float*)d_out;
    float* ws  = (float*)d_ws;   // needs 4096*81*4 = 1.33 MB

    // 32768 rows / 16 rows per block (8 waves x 2 rows)
    emis_kernel<<<2048, 512, 0, stream>>>(embed, W, bias, out);
    // 4096 chunk-waves / 4 waves per block
    crf_chunk<<<1024, 256, 0, stream>>>(out, mask, trans, ws);
    // one block per batch
    crf_final<<<BB, 256, 0, stream>>>(out, tags, mask, start_t, end_t, trans, ws, out);
}